// Round 12
// baseline (144.122 us; speedup 1.0000x reference)
//
#include <hip/hip_runtime.h>

namespace {

constexpr int L           = 128;
constexpr int NANG        = 120;
constexpr int SLICE_BYTES = L * L * 4;   // 65536 = 1<<16
constexpr int ROW_BYTES   = L * 4;       // 512

typedef __fp16 f16x2 __attribute__((ext_vector_type(2)));
typedef __fp16 f16x4 __attribute__((ext_vector_type(4)));
typedef float  f32x4 __attribute__((ext_vector_type(4)));

// Block: 1024 thr = 16 waves. Tile: 8(x) x 4(y) = 32 points, both b, all 128 z.
// Wave w: b = w&1, zq3 = w>>1 (16-z eighth); computes BOTH 16-point M-tiles on
// its single 16-z chunk -> 8 outputs/lane. 512 blocks x 1024 thr = 32 waves/CU
// (8 waves/SIMD): latency hiding via TLP, not compiler-fragile ILP.
// Direct-from-global B-fragments (L1/L2-hot), SGPR load bases, 3-slot rotating
// prefetch (depth 2 angles), no barriers in the main loop.
__global__ __launch_bounds__(1024, 8) void bp_kernel(
    const float* __restrict__ image,   // [2,120,128,128] f32
    const float* __restrict__ angles,  // [120] deg
    float* __restrict__ out)           // [2,128,128,128] f32
{
    __shared__ alignas(16) uint2 wtab[NANG * 32];  // 30 KiB: [a][p] {w0|w1<<16, s0}
    __shared__ float2   acs[NANG];
    __shared__ unsigned arlo[NANG];                // per-angle first row (<= 116)
    __shared__ alignas(16) float nrmtab[32];

    const int tid = threadIdx.x;
    const int yb  = blockIdx.x * 4;
    const int xb  = blockIdx.y * 8;
    const float cx = (L - 1) * 0.5f;

    // ---- Phase 0: per-angle rotation params + tile row floor ----
    if (tid < NANG) {
        const float phi = -angles[tid] * 0.017453292519943295f;
        float s, c;
        sincosf(phi, &s, &c);
        const float X0 = (float)xb - cx,       X1 = (float)(xb + 7) - cx;
        const float Y0 = (float)yb - cx,       Y1 = (float)(yb + 3) - cx;
        const float a00 = -s * X0 + c * Y0 + cx;
        const float a01 = -s * X0 + c * Y1 + cx;
        const float a10 = -s * X1 + c * Y0 + cx;
        const float a11 = -s * X1 + c * Y1 + cx;
        const float symin = fminf(fminf(a00, a01), fminf(a10, a11));
        acs[tid]  = make_float2(c, s);
        // rlo <= 116 so rows rlo..rlo+11 are always in-bounds (window still
        // covers all nonzero-weight rows: span <= 12, rows <= 127).
        arlo[tid] = (unsigned)min(max((int)floorf(symin) - 1, 0), 116);
    }
    if (tid < 32) nrmtab[tid] = 0.f;
    __syncthreads();

    // ---- Phase 1: per-(point,angle) entry {f16 w0|w1, s0}; s1 == s0+1 implicit ----
    for (int e = tid; e < 32 * NANG; e += 1024) {
        const int p = e / NANG;
        const int a = e - p * NANG;
        const float2 cs = acs[a];
        const int rlo = (int)arlo[a];
        const float X = (float)(xb + (p >> 2)) - cx;
        const float Y = (float)(yb + (p & 3)) - cx;
        const float sx =  cs.x * X + cs.y * Y + cx;
        const float sy = -cs.y * X + cs.x * Y + cx;
        const float x0f = floorf(sx), y0f = floorf(sy);
        const float wx = sx - x0f,    wy = sy - y0f;
        const int x0 = (int)x0f, y0 = (int)y0f;
        const float mx0 = (x0 >= 0  && x0 <  L)     ? 1.f : 0.f;
        const float mx1 = (x0 >= -1 && x0 <= L - 2) ? 1.f : 0.f;
        const float my0 = (y0 >= 0  && y0 <  L)     ? 1.f : 0.f;
        const float my1 = (y0 >= -1 && y0 <= L - 2) ? 1.f : 0.f;
        const float A   = (1.f - wx) * mx0 + wx * mx1;
        float w0f = (1.f - wy) * my0 * A;
        float w1f = wy * my1 * A;
        const int y0c = min(max(y0, 0), L - 1);
        const int y1c = min(max(y0 + 1, 0), L - 1);
        const int s0  = min(max(y0c - rlo, 0), 11);
        const int s1  = min(max(y1c - rlo, 0), 11);
        // Boundary clamp collision (s1==s0): fold w1 into w0 (exact: one mask is 0).
        // Guarantees nonzero weights only at k <= 11 (quad 3 is always A=0).
        if (s0 == s1) { w0f += w1f; w1f = 0.f; }
        f16x2 wh = __builtin_amdgcn_cvt_pkrtz(w0f, w1f);
        uint2 ent;
        ent.x = *reinterpret_cast<unsigned*>(&wh);
        ent.y = (unsigned)s0;
        wtab[a * 32 + p] = ent;
        atomicAdd(&nrmtab[p], w0f + w1f);
    }
    __syncthreads();   // the ONLY barrier before the epilogue

    const int wave  = tid >> 6;
    const int lane  = tid & 63;
    const int quad  = lane >> 4;
    const int lhalf = lane & 15;
    const int b     = wave & 1;
    const int zq3   = wave >> 1;               // 0..7, 16 z's each
    const char* __restrict__ imgc = (const char*)image;

    // Wave-uniform scalar slice base; per-lane 32-bit row/col offsets.
    const unsigned bbase_s = __builtin_amdgcn_readfirstlane((unsigned)(b * NANG) * SLICE_BYTES);
    const unsigned zoff0   = (unsigned)(zq3 * 16 + lhalf) * 4u;
    const int quad4 = (quad == 3) ? 0 : (quad * 4);   // quad3 re-reads quad0's rows (A=0 there)
    unsigned qz[4];
#pragma unroll
    for (int j = 0; j < 4; ++j) qz[j] = (unsigned)(quad4 + j) * ROW_BYTES + zoff0;

    f32x4 acc[2] = {};   // [mt]

    // A-fragment: nonzeros at k=s0 (w0), k=s0+1 (w1); element j of quad's 64-bit window.
    auto build_af = [&](uint2 e) -> f16x4 {
        const unsigned s0 = e.y;
        const unsigned t  = s0 & 3u;
        const int      q0 = (int)(s0 >> 2);
        const unsigned long long W = (unsigned long long)e.x << (t * 16u);
        const unsigned spill = (t == 3u) ? (e.x >> 16) : 0u;
        const unsigned long long af64 =
            (quad == q0) ? W : ((quad == q0 + 1) ? (unsigned long long)spill : 0ull);
        union { unsigned long long u; f16x4 v; } c; c.u = af64; return c.v;
    };

    auto read_tab = [&](int a, uint2* tA, uint2* tB, unsigned* rl) {
        *tA = wtab[a * 32 + lhalf];
        *tB = wtab[a * 32 + 16 + lhalf];
        *rl = __builtin_amdgcn_readfirstlane(arlo[a]);
    };
    // 4 scalar loads for this wave's 16-z chunk of angle a
    auto issue1 = [&](int a, unsigned rl, float* r) {
        const char* pa = imgc + (bbase_s + ((unsigned)a << 16) + (rl << 9)); // SGPR base
#pragma unroll
        for (int j = 0; j < 4; ++j) r[j] = *(const float*)(pa + qz[j]);
    };
    auto compute = [&](uint2 eA, uint2 eB, const float* r) {
        const f16x4 af0 = build_af(eA);
        const f16x4 af1 = build_af(eB);
        const f16x2 h01 = __builtin_amdgcn_cvt_pkrtz(r[0], r[1]);
        const f16x2 h23 = __builtin_amdgcn_cvt_pkrtz(r[2], r[3]);
        const f16x4 bf = {h01.x, h01.y, h23.x, h23.y};
        acc[0] = __builtin_amdgcn_mfma_f32_16x16x16f16(af0, bf, acc[0], 0, 0, 0);
        acc[1] = __builtin_amdgcn_mfma_f32_16x16x16f16(af1, bf, acc[1], 0, 0, 0);
    };

    // ---- Main loop: 3-slot rotating prefetch, depth 2 angles ----
    uint2 A0, B0, A1, B1, A2, B2;
    unsigned R0, R1, R2;
    float rb0[4], rb1[4], rb2[4];

    read_tab(0, &A0, &B0, &R0); issue1(0, R0, rb0);
    read_tab(1, &A1, &B1, &R1); issue1(1, R1, rb1);

    for (int a = 0; a < NANG; a += 3) {
        if (a + 2 < NANG) { read_tab(a + 2, &A2, &B2, &R2); issue1(a + 2, R2, rb2); }
        compute(A0, B0, rb0);
        if (a + 3 < NANG) { read_tab(a + 3, &A0, &B0, &R0); issue1(a + 3, R0, rb0); }
        compute(A1, B1, rb1);
        if (a + 4 < NANG) { read_tab(a + 4, &A1, &B1, &R1); issue1(a + 4, R1, rb1); }
        compute(A2, B2, rb2);
    }

    // ---- Epilogue: D[row=quad*4+r][col=lhalf], point p = mt*16+quad*4+r ----
    const int z = zq3 * 16 + lhalf;
#pragma unroll
    for (int mt = 0; mt < 2; ++mt) {
        const float4 nrm4 = *(const float4*)&nrmtab[mt * 16 + quad * 4];
        const float iv[4] = { 1.f / (nrm4.x + 1e-11f), 1.f / (nrm4.y + 1e-11f),
                              1.f / (nrm4.z + 1e-11f), 1.f / (nrm4.w + 1e-11f) };
#pragma unroll
        for (int r = 0; r < 4; ++r) {
            const int p = mt * 16 + quad * 4 + r;
            const int x = xb + (p >> 2);
            const int y = yb + (p & 3);
            out[(((size_t)(b * L + x)) * L + y) * L + z] = acc[mt][r] * iv[r];
        }
    }
}

} // namespace

extern "C" void kernel_launch(void* const* d_in, const int* in_sizes, int n_in,
                              void* d_out, int out_size, void* d_ws, size_t ws_size,
                              hipStream_t stream) {
    const float* image  = (const float*)d_in[0];
    const float* angles = (const float*)d_in[1];
    float* out = (float*)d_out;
    (void)in_sizes; (void)n_in; (void)out_size; (void)d_ws; (void)ws_size;

    dim3 grid(L / 4, L / 8);   // 32 x 16 = 512 blocks of 1024 thr = 2 per CU, 32 waves/CU
    bp_kernel<<<grid, 1024, 0, stream>>>(image, angles, out);
}

// Round 13
// 134.986 us; speedup vs baseline: 1.0677x; 1.0677x over previous
//
#include <hip/hip_runtime.h>

namespace {

constexpr int L           = 128;
constexpr int NANG        = 120;
constexpr int SLICE_BYTES = L * L * 4;   // 65536 = 1<<16
constexpr int ROW_BYTES   = L * 4;       // 512

typedef __fp16 f16x2 __attribute__((ext_vector_type(2)));
typedef __fp16 f16x4 __attribute__((ext_vector_type(4)));
typedef float  f32x4 __attribute__((ext_vector_type(4)));

// Block: 1024 thr = 16 waves. Tile: 8(x) x 4(y) = 32 points, both b, all 128 z.
// Wave w: b = w&1, zq3 = w>>1 (16-z eighth); computes BOTH 16-point M-tiles on
// its 16-z chunk. 512 blocks x 1024 thr = 32 waves/CU (8/SIMD).
// Key change vs R12: A-fragments are PRE-SHIFTED in phase 1 into a 16B LDS
// entry {W_lo, W_hi, spill, q0|rlo<<8}; in-loop build is 2 cmp + 3 cndmask.
__global__ __launch_bounds__(1024, 8) void bp_kernel(
    const float* __restrict__ image,   // [2,120,128,128] f32
    const float* __restrict__ angles,  // [120] deg
    float* __restrict__ out)           // [2,128,128,128] f32
{
    __shared__ alignas(16) uint4 wtab[NANG * 32];  // 60 KiB: [a][p] pre-shifted A entry
    __shared__ float2   acs[NANG];
    __shared__ unsigned arlo[NANG];                // per-angle first row (<= 116)
    __shared__ alignas(16) float nrmtab[32];

    const int tid = threadIdx.x;
    const int yb  = blockIdx.x * 4;
    const int xb  = blockIdx.y * 8;
    const float cx = (L - 1) * 0.5f;

    // ---- Phase 0: per-angle rotation params + tile row floor ----
    if (tid < NANG) {
        const float phi = -angles[tid] * 0.017453292519943295f;
        float s, c;
        sincosf(phi, &s, &c);
        const float X0 = (float)xb - cx,       X1 = (float)(xb + 7) - cx;
        const float Y0 = (float)yb - cx,       Y1 = (float)(yb + 3) - cx;
        const float a00 = -s * X0 + c * Y0 + cx;
        const float a01 = -s * X0 + c * Y1 + cx;
        const float a10 = -s * X1 + c * Y0 + cx;
        const float a11 = -s * X1 + c * Y1 + cx;
        const float symin = fminf(fminf(a00, a01), fminf(a10, a11));
        acs[tid]  = make_float2(c, s);
        // rlo <= 116 so rows rlo..rlo+11 are always in-bounds (window still
        // covers all nonzero-weight rows: span <= 12, rows <= 127).
        arlo[tid] = (unsigned)min(max((int)floorf(symin) - 1, 0), 116);
    }
    if (tid < 32) nrmtab[tid] = 0.f;
    __syncthreads();

    // ---- Phase 1: per-(point,angle) pre-shifted A entry ----
    // Weight pair (w0@k=s0, w1@k=s0+1) as a 64-bit window: W = (w0|w1<<16) << (16*(s0&3))
    // lands in quad q0 = s0>>2; spill = w1 when s0&3==3 (goes to quad q0+1, elem 0).
    for (int e = tid; e < 32 * NANG; e += 1024) {
        const int p = e / NANG;
        const int a = e - p * NANG;
        const float2 cs = acs[a];
        const int rlo = (int)arlo[a];
        const float X = (float)(xb + (p >> 2)) - cx;
        const float Y = (float)(yb + (p & 3)) - cx;
        const float sx =  cs.x * X + cs.y * Y + cx;
        const float sy = -cs.y * X + cs.x * Y + cx;
        const float x0f = floorf(sx), y0f = floorf(sy);
        const float wx = sx - x0f,    wy = sy - y0f;
        const int x0 = (int)x0f, y0 = (int)y0f;
        const float mx0 = (x0 >= 0  && x0 <  L)     ? 1.f : 0.f;
        const float mx1 = (x0 >= -1 && x0 <= L - 2) ? 1.f : 0.f;
        const float my0 = (y0 >= 0  && y0 <  L)     ? 1.f : 0.f;
        const float my1 = (y0 >= -1 && y0 <= L - 2) ? 1.f : 0.f;
        const float A   = (1.f - wx) * mx0 + wx * mx1;
        float w0f = (1.f - wy) * my0 * A;
        float w1f = wy * my1 * A;
        const int y0c = min(max(y0, 0), L - 1);
        const int y1c = min(max(y0 + 1, 0), L - 1);
        const int s0  = min(max(y0c - rlo, 0), 11);
        const int s1  = min(max(y1c - rlo, 0), 11);
        // Boundary clamp collision (s1==s0, incl. s0==11): fold w1 into w0
        // (exact: one mask is 0). Nonzero weights then live only at k <= 11.
        if (s0 == s1) { w0f += w1f; w1f = 0.f; }
        f16x2 wh = __builtin_amdgcn_cvt_pkrtz(w0f, w1f);
        const unsigned ex = *reinterpret_cast<unsigned*>(&wh);
        const unsigned t  = (unsigned)(s0 & 3);
        const unsigned q0 = (unsigned)(s0 >> 2);
        const unsigned long long W = (unsigned long long)ex << (t * 16u);
        uint4 ent;
        ent.x = (unsigned)W;
        ent.y = (unsigned)(W >> 32);
        ent.z = (t == 3u) ? (ex >> 16) : 0u;   // w1 spill into quad q0+1 elem 0
        ent.w = q0 | ((unsigned)arlo[a] << 8);
        wtab[a * 32 + p] = ent;
        atomicAdd(&nrmtab[p], w0f + w1f);
    }
    __syncthreads();   // the ONLY barrier before the epilogue

    const int wave  = tid >> 6;
    const int lane  = tid & 63;
    const int quad  = lane >> 4;
    const int lhalf = lane & 15;
    const int b     = wave & 1;
    const int zq3   = wave >> 1;               // 0..7, 16 z's each
    const char* __restrict__ imgc = (const char*)image;

    // Wave-uniform scalar slice base; per-lane 32-bit row/col offsets.
    const unsigned bbase_s = __builtin_amdgcn_readfirstlane((unsigned)(b * NANG) * SLICE_BYTES);
    const unsigned zoff0   = (unsigned)(zq3 * 16 + lhalf) * 4u;
    const int quad4 = (quad == 3) ? 0 : (quad * 4);   // quad3 re-reads quad0's rows (A=0 there)
    unsigned qz[4];
#pragma unroll
    for (int j = 0; j < 4; ++j) qz[j] = (unsigned)(quad4 + j) * ROW_BYTES + zoff0;

    f32x4 acc[2] = {};   // [mt]

    // In-loop A-fragment: 2 compares + 3 cndmasks.
    auto build_af = [&](uint4 e) -> f16x4 {
        const int q0 = (int)(e.w & 0xffu);
        const unsigned lo = (quad == q0) ? e.x : ((quad == q0 + 1) ? e.z : 0u);
        const unsigned hi = (quad == q0) ? e.y : 0u;
        union { unsigned u[2]; f16x4 v; } c;
        c.u[0] = lo; c.u[1] = hi;
        return c.v;
    };

    auto read_tab = [&](int a, uint4* tA, uint4* tB, unsigned* rl) {
        *tA = wtab[a * 32 + lhalf];          // ds_read_b128 broadcast
        *tB = wtab[a * 32 + 16 + lhalf];
        *rl = __builtin_amdgcn_readfirstlane(tA->w) >> 8;
    };
    // 4 scalar loads for this wave's 16-z chunk of angle a (SGPR base + imm-ready voffsets)
    auto issue1 = [&](int a, unsigned rl, float* r) {
        const char* pa = imgc + (bbase_s + ((unsigned)a << 16) + (rl << 9));
#pragma unroll
        for (int j = 0; j < 4; ++j) r[j] = *(const float*)(pa + qz[j]);
    };
    auto compute = [&](uint4 eA, uint4 eB, const float* r) {
        const f16x4 af0 = build_af(eA);
        const f16x4 af1 = build_af(eB);
        const f16x2 h01 = __builtin_amdgcn_cvt_pkrtz(r[0], r[1]);
        const f16x2 h23 = __builtin_amdgcn_cvt_pkrtz(r[2], r[3]);
        const f16x4 bf = {h01.x, h01.y, h23.x, h23.y};
        acc[0] = __builtin_amdgcn_mfma_f32_16x16x16f16(af0, bf, acc[0], 0, 0, 0);
        acc[1] = __builtin_amdgcn_mfma_f32_16x16x16f16(af1, bf, acc[1], 0, 0, 0);
    };

    // ---- Main loop: 3-slot rotating prefetch, depth 2 angles, no barriers ----
    uint4 A0, B0, A1, B1, A2, B2;
    unsigned R0, R1, R2;
    float rb0[4], rb1[4], rb2[4];

    read_tab(0, &A0, &B0, &R0); issue1(0, R0, rb0);
    read_tab(1, &A1, &B1, &R1); issue1(1, R1, rb1);

    for (int a = 0; a < NANG; a += 3) {
        if (a + 2 < NANG) { read_tab(a + 2, &A2, &B2, &R2); issue1(a + 2, R2, rb2); }
        compute(A0, B0, rb0);
        if (a + 3 < NANG) { read_tab(a + 3, &A0, &B0, &R0); issue1(a + 3, R0, rb0); }
        compute(A1, B1, rb1);
        if (a + 4 < NANG) { read_tab(a + 4, &A1, &B1, &R1); issue1(a + 4, R1, rb1); }
        compute(A2, B2, rb2);
    }

    // ---- Epilogue: D[row=quad*4+r][col=lhalf], point p = mt*16+quad*4+r ----
    const int z = zq3 * 16 + lhalf;
#pragma unroll
    for (int mt = 0; mt < 2; ++mt) {
        const float4 nrm4 = *(const float4*)&nrmtab[mt * 16 + quad * 4];
        const float iv[4] = { 1.f / (nrm4.x + 1e-11f), 1.f / (nrm4.y + 1e-11f),
                              1.f / (nrm4.z + 1e-11f), 1.f / (nrm4.w + 1e-11f) };
#pragma unroll
        for (int r = 0; r < 4; ++r) {
            const int p = mt * 16 + quad * 4 + r;
            const int x = xb + (p >> 2);
            const int y = yb + (p & 3);
            out[(((size_t)(b * L + x)) * L + y) * L + z] = acc[mt][r] * iv[r];
        }
    }
}

} // namespace

extern "C" void kernel_launch(void* const* d_in, const int* in_sizes, int n_in,
                              void* d_out, int out_size, void* d_ws, size_t ws_size,
                              hipStream_t stream) {
    const float* image  = (const float*)d_in[0];
    const float* angles = (const float*)d_in[1];
    float* out = (float*)d_out;
    (void)in_sizes; (void)n_in; (void)out_size; (void)d_ws; (void)ws_size;

    dim3 grid(L / 4, L / 8);   // 32 x 16 = 512 blocks of 1024 thr = 2/CU, 32 waves/CU
    bp_kernel<<<grid, 1024, 0, stream>>>(image, angles, out);
}